// Round 4
// baseline (419.251 us; speedup 1.0000x reference)
//
#include <hip/hip_runtime.h>

#define Q_INV (1.0f / 128.0f)

__device__ __forceinline__ float quant_comp_f(float v) {
    // v*128 is exact (pow2 scale); floor/clamp/or-1 exactly as reference
    float f = floorf(v * 128.0f);
    f = fminf(fmaxf(f, -128.0f), 127.0f);
    int qi = (int)f;
    qi |= 1;
    return (float)qi * Q_INV;
}

// One block per image. Emulate golden fp32 semantics: zero-init accumulator,
// single ascending-k fmaf chain with conv contraction order (ky, kx, ic)
// [channel-minor / NHWC patch order, as XLA-CPU/Eigen im2col produces],
// bias added as a separate rounded add, then relu/pool/quant.
__global__ __launch_bounds__(256) void conv_fused_kernel(
    const float* __restrict__ x,
    const float* __restrict__ c1w, const float* __restrict__ c1b,
    const float* __restrict__ c2w, const float* __restrict__ c2b,
    const int* __restrict__ qflag,
    float* __restrict__ act)
{
    __shared__ float pin[32][33];     // padded input (pad=2), zeroed border
    __shared__ float w1[6][25];
    __shared__ float b1s[6];
    __shared__ float mid[6][14][18];  // cols 14..17 stay zero (OOB-safe tile reads)
    __shared__ float w2[2400];        // [16][6][25]
    __shared__ float b2s[16];

    const int t = threadIdx.x;
    const int img = blockIdx.x;
    const bool q = (qflag[0] != 0);

    for (int i = t; i < 32 * 33; i += 256) (&pin[0][0])[i] = 0.0f;
    for (int i = t; i < 6 * 14 * 18; i += 256) (&mid[0][0][0])[i] = 0.0f;
    if (t < 150) (&w1[0][0])[t] = c1w[t];
    if (t < 6) b1s[t] = c1b[t];
    for (int i = t; i < 2400; i += 256) w2[i] = c2w[i];
    if (t < 16) b2s[t] = c2b[t];
    __syncthreads();

    const float* xi = x + (size_t)img * 784;
    for (int i = t; i < 784; i += 256) {
        float v = xi[i];
        if (q) v = quant_comp_f(v);
        pin[i / 28 + 2][i % 28 + 2] = v;
    }
    __syncthreads();

    // conv1 phase: 588 items, each computes 2 adjacent pooled outputs.
    // C=1: k-order (ky,kx) — matches channel-minor patch order trivially.
    for (int item = t; item < 588; item += 256) {
        const int c = item / 98;
        const int rem = item % 98;
        const int ph = rem / 7;
        const int pw0 = 2 * (rem % 7);
        float wr[25];
        #pragma unroll
        for (int k = 0; k < 25; ++k) wr[k] = w1[c][k];
        float s[8];
        #pragma unroll
        for (int j = 0; j < 8; ++j) s[j] = 0.0f;
        const int oh = 2 * ph;
        const int ow = 2 * pw0;
        #pragma unroll
        for (int ky = 0; ky < 5; ++ky) {
            #pragma unroll
            for (int kx = 0; kx < 5; ++kx) {
                const float wv = wr[ky * 5 + kx];
                #pragma unroll
                for (int dy = 0; dy < 2; ++dy)
                    #pragma unroll
                    for (int dx = 0; dx < 4; ++dx)
                        s[dy * 4 + dx] = fmaf(pin[oh + dy + ky][ow + dx + kx], wv,
                                              s[dy * 4 + dx]);
            }
        }
        const float bb = b1s[c];
        float v[8];
        #pragma unroll
        for (int j = 0; j < 8; ++j) v[j] = s[j] + bb;   // separate rounded add
        float m0 = fmaxf(fmaxf(v[0], v[1]), fmaxf(v[4], v[5]));
        float m1 = fmaxf(fmaxf(v[2], v[3]), fmaxf(v[6], v[7]));
        m0 = fmaxf(m0, 0.0f); m1 = fmaxf(m1, 0.0f);
        if (q) { m0 = quant_comp_f(m0); m1 = quant_comp_f(m1); }
        mid[c][ph][pw0] = m0;
        mid[c][ph][pw0 + 1] = m1;
    }
    __syncthreads();

    // conv2 phase: 240 items = 16c x 5ph x 3 pw-pairs (last pair covers 1).
    // k-order (ky, kx, ic) with ic INNERMOST — single fmaf chain per output.
    float* ao = act + (size_t)img * 400;
    for (int item = t; item < 240; item += 256) {
        const int c = item / 15;
        const int rem = item % 15;
        const int ph = rem / 3;
        const int pj = rem % 3;
        const int pw0 = 2 * pj;
        float acc[2][4];
        #pragma unroll
        for (int dy = 0; dy < 2; ++dy)
            #pragma unroll
            for (int dx = 0; dx < 4; ++dx) acc[dy][dx] = 0.0f;
        #pragma unroll
        for (int ky = 0; ky < 5; ++ky) {
            #pragma unroll
            for (int kx = 0; kx < 5; ++kx) {
                #pragma unroll
                for (int ic = 0; ic < 6; ++ic) {
                    const float wv = w2[(c * 6 + ic) * 25 + ky * 5 + kx];
                    #pragma unroll
                    for (int dy = 0; dy < 2; ++dy)
                        #pragma unroll
                        for (int dx = 0; dx < 4; ++dx)
                            acc[dy][dx] = fmaf(mid[ic][2 * ph + dy + ky][2 * pw0 + dx + kx],
                                               wv, acc[dy][dx]);
                }
            }
        }
        const float bb = b2s[c];
        float v[2][4];
        #pragma unroll
        for (int dy = 0; dy < 2; ++dy)
            #pragma unroll
            for (int dx = 0; dx < 4; ++dx) v[dy][dx] = acc[dy][dx] + bb;
        float m0 = fmaxf(fmaxf(v[0][0], v[0][1]), fmaxf(v[1][0], v[1][1]));
        float m1 = fmaxf(fmaxf(v[0][2], v[0][3]), fmaxf(v[1][2], v[1][3]));
        m0 = fmaxf(m0, 0.0f); m1 = fmaxf(m1, 0.0f);
        if (q) { m0 = quant_comp_f(m0); m1 = quant_comp_f(m1); }
        const int o = c * 25 + ph * 5 + pw0;
        ao[o] = m0;
        if (pj < 2) ao[o + 1] = m1;
    }
}

// 16 images per block; lanes = images so weight-row loads are group-uniform.
// acc=0, ascending-k single fmaf chain, bias as separate rounded add.
__global__ __launch_bounds__(256) void fc_fused_kernel(
    const float* __restrict__ act,                       // [B,400] quantized
    const float* __restrict__ w1, const float* __restrict__ b1,  // [120,400]
    const float* __restrict__ w2, const float* __restrict__ b2,  // [84,120]
    const float* __restrict__ w3, const float* __restrict__ b3,  // [10,84]
    const int* __restrict__ qflag,
    float* __restrict__ out, int B)
{
    __shared__ __align__(16) float a0[16][404];
    __shared__ __align__(16) float a1[16][124];
    __shared__ __align__(16) float a2[16][88];

    const int t = threadIdx.x;
    const bool q = (qflag[0] != 0);
    const int base = blockIdx.x * 16;

    for (int i = t; i < 16 * 400; i += 256) {
        const int im = i / 400, k = i % 400;
        if (base + im < B) a0[im][k] = act[(size_t)(base + im) * 400 + k];
    }
    __syncthreads();

    const int im = t & 15;
    const int grp = t >> 4;

    // fc1: 120 outs, k=400
    for (int o = grp; o < 120; o += 16) {
        const float4* wr = reinterpret_cast<const float4*>(w1 + o * 400);
        const float4* ar = reinterpret_cast<const float4*>(&a0[im][0]);
        float acc = 0.0f;
        #pragma unroll 4
        for (int kk = 0; kk < 100; ++kk) {
            const float4 av = ar[kk];
            const float4 wv = wr[kk];
            acc = fmaf(av.x, wv.x, acc);
            acc = fmaf(av.y, wv.y, acc);
            acc = fmaf(av.z, wv.z, acc);
            acc = fmaf(av.w, wv.w, acc);
        }
        float v = acc + b1[o];         // separate rounded add
        v = fmaxf(v, 0.0f);
        a1[im][o] = q ? quant_comp_f(v) : v;
    }
    __syncthreads();

    // fc2: 84 outs, k=120
    for (int o = grp; o < 84; o += 16) {
        const float4* wr = reinterpret_cast<const float4*>(w2 + o * 120);
        const float4* ar = reinterpret_cast<const float4*>(&a1[im][0]);
        float acc = 0.0f;
        #pragma unroll 4
        for (int kk = 0; kk < 30; ++kk) {
            const float4 av = ar[kk];
            const float4 wv = wr[kk];
            acc = fmaf(av.x, wv.x, acc);
            acc = fmaf(av.y, wv.y, acc);
            acc = fmaf(av.z, wv.z, acc);
            acc = fmaf(av.w, wv.w, acc);
        }
        float v = acc + b2[o];
        v = fmaxf(v, 0.0f);
        a2[im][o] = q ? quant_comp_f(v) : v;
    }
    __syncthreads();

    // fc3: 10 outs, k=84
    for (int o = grp; o < 10; o += 16) {
        const float4* wr = reinterpret_cast<const float4*>(w3 + o * 84);
        const float4* ar = reinterpret_cast<const float4*>(&a2[im][0]);
        float acc = 0.0f;
        #pragma unroll
        for (int kk = 0; kk < 21; ++kk) {
            const float4 av = ar[kk];
            const float4 wv = wr[kk];
            acc = fmaf(av.x, wv.x, acc);
            acc = fmaf(av.y, wv.y, acc);
            acc = fmaf(av.z, wv.z, acc);
            acc = fmaf(av.w, wv.w, acc);
        }
        if (base + im < B) out[(size_t)(base + im) * 10 + o] = acc + b3[o];
    }
}

extern "C" void kernel_launch(void* const* d_in, const int* in_sizes, int n_in,
                              void* d_out, int out_size, void* d_ws, size_t ws_size,
                              hipStream_t stream) {
    const float* x     = (const float*)d_in[0];
    const float* c1w   = (const float*)d_in[1];
    const float* c1b   = (const float*)d_in[2];
    const float* c2w   = (const float*)d_in[3];
    const float* c2b   = (const float*)d_in[4];
    const float* fc1w  = (const float*)d_in[5];
    const float* fc1b  = (const float*)d_in[6];
    const float* fc2w  = (const float*)d_in[7];
    const float* fc2b  = (const float*)d_in[8];
    const float* fc3w  = (const float*)d_in[9];
    const float* fc3b  = (const float*)d_in[10];
    const int*   qflag = (const int*)d_in[11];
    float* out = (float*)d_out;

    const int B = in_sizes[0] / 784;
    float* act = (float*)d_ws;  // [B,400]

    conv_fused_kernel<<<B, 256, 0, stream>>>(x, c1w, c1b, c2w, c2b, qflag, act);

    const int nblk = (B + 15) / 16;
    fc_fused_kernel<<<nblk, 256, 0, stream>>>(act, fc1w, fc1b, fc2w, fc2b,
                                              fc3w, fc3b, qflag, out, B);
}